// Round 5
// baseline (606.800 us; speedup 1.0000x reference)
//
#include <hip/hip_runtime.h>
#include <stdint.h>

// Problem (fp32 in / fp32 out): out = relu((x + (x@Wv^T+bv)@Wo^T + bo) @ Wn^T + bn)
//   softmax over a single score == 1 -> q,k path is dead code.
// Round 5 structure:
//   Vp[ks] = x@Wv^T partials (split-K=4, fp32, in d_out scratch)   [k_v]
//   Wnb = bf16(Wn)                                                  [k_cvtWn]
//   hb  = bf16(x + (sum Vp + bv)@Wo^T + bo)                         [k_h]
//   out = relu(hb@Wnb^T + bn)                                       [k_main, round-4 proven]

typedef unsigned short u16;
typedef float f32x4 __attribute__((ext_vector_type(4)));
typedef __bf16 bf16x8 __attribute__((ext_vector_type(8)));
typedef u16 u16x8 __attribute__((ext_vector_type(8)));

__device__ __forceinline__ u16 f2b(float f) {  // round-to-nearest-even
  union { float f; unsigned int i; } x; x.f = f;
  unsigned int r = x.i + 0x7FFFu + ((x.i >> 16) & 1u);
  return (u16)(r >> 16);
}

// async global->LDS, 16B per lane; lds base wave-uniform (lane lands at base + lane*16B)
__device__ __forceinline__ void gl_lds16(const u16* g, u16* l) {
#if __has_builtin(__builtin_amdgcn_global_load_lds)
  __builtin_amdgcn_global_load_lds((__attribute__((address_space(1))) void*)g,
                                   (__attribute__((address_space(3))) void*)l, 16, 0, 0);
#else
  int lane = threadIdx.x & 63;
  *(u16x8*)(l + lane * 8) = *(const u16x8*)g;
#endif
}

__device__ __forceinline__ f32x4 mfma16(bf16x8 a, bf16x8 b, f32x4 c) {
  return __builtin_amdgcn_mfma_f32_16x16x32_bf16(a, b, c, 0, 0, 0);
}

__device__ __forceinline__ void cvt16(const float* s, u16* d0, u16* d1) {
  f32x4 a0 = *(const f32x4*)s, a1 = *(const f32x4*)(s + 4);
  f32x4 a2 = *(const f32x4*)(s + 8), a3 = *(const f32x4*)(s + 12);
  u16x8 o0, o1;
#pragma unroll
  for (int e = 0; e < 4; ++e) { o0[e] = f2b(a0[e]); o0[4 + e] = f2b(a1[e]); }
#pragma unroll
  for (int e = 0; e < 4; ++e) { o1[e] = f2b(a2[e]); o1[4 + e] = f2b(a3[e]); }
  *(u16x8*)d0 = o0; *(u16x8*)d1 = o1;
}

// ---------------------------------------------------------------------------
// k_v: Vp[ks][8192][64] = x[:, ks*1024:+1024] @ Wv[:, same]^T   (fp32 partials)
//   grid 512 = 128 m-blocks (64 rows) x 4 k-splits; BK=64, 16 iters.
//   Staging: fp32 global -> VALU convert -> LDS (stride 72: 2-way alias, free).
// ---------------------------------------------------------------------------
__global__ __launch_bounds__(256, 2) void k_v(
    const float* __restrict__ x, const float* __restrict__ Wv, float* __restrict__ Vp) {
  __shared__ __align__(16) u16 lA[64 * 72];
  __shared__ __align__(16) u16 lB[64 * 72];
  const int tid = threadIdx.x;
  const int w = tid >> 6, l = tid & 63;
  const long m0 = (long)(blockIdx.x >> 2) * 64;
  const int kbase = (int)(blockIdx.x & 3) * 1024;
  f32x4 acc[4];
#pragma unroll
  for (int nt = 0; nt < 4; ++nt) acc[nt] = (f32x4)(0.f);

  const int srow = tid >> 2, sc = (tid & 3) * 16;
  for (int it = 0; it < 16; ++it) {
    const int k0 = kbase + it * 64;
    __syncthreads();
    cvt16(&x[(m0 + srow) * 4096 + k0 + sc], &lA[srow * 72 + sc], &lA[srow * 72 + sc + 8]);
    cvt16(&Wv[(long)srow * 4096 + k0 + sc], &lB[srow * 72 + sc], &lB[srow * 72 + sc + 8]);
    __syncthreads();
#pragma unroll
    for (int kk = 0; kk < 2; ++kk) {
      const int ko = kk * 32 + (l >> 4) * 8;
      bf16x8 af = *(const bf16x8*)&lA[(w * 16 + (l & 15)) * 72 + ko];
#pragma unroll
      for (int nt = 0; nt < 4; ++nt) {
        bf16x8 bf = *(const bf16x8*)&lB[(nt * 16 + (l & 15)) * 72 + ko];
        acc[nt] = mfma16(af, bf, acc[nt]);
      }
    }
  }
  const long ksoff = (long)(blockIdx.x & 3) * 8192;
#pragma unroll
  for (int nt = 0; nt < 4; ++nt) {
    int col = nt * 16 + (l & 15);
#pragma unroll
    for (int r = 0; r < 4; ++r) {
      long row = m0 + w * 16 + (l >> 4) * 4 + r;
      Vp[(ksoff + row) * 64 + col] = acc[nt][r];
    }
  }
}

// ---------------------------------------------------------------------------
// k_cvtWn: Wn fp32 -> bf16, streaming, 8 floats/thread.
// ---------------------------------------------------------------------------
__global__ __launch_bounds__(256) void k_cvtWn(const float* __restrict__ Wn,
                                               u16* __restrict__ Wnb) {
  long off = ((long)blockIdx.x * 256 + threadIdx.x) * 8;
  f32x4 a = *(const f32x4*)&Wn[off];
  f32x4 b = *(const f32x4*)&Wn[off + 4];
  u16x8 o;
#pragma unroll
  for (int e = 0; e < 4; ++e) { o[e] = f2b(a[e]); o[4 + e] = f2b(b[e]); }
  *(u16x8*)&Wnb[off] = o;
}

// ---------------------------------------------------------------------------
// k_h: hb[m][c] = bf16( x[m][c] + sum_a v[m][a]*Wo[c][a] + bo[c] )
//   v = sum_ks Vp + bv. grid 2048 = 128 m-blocks (64 rows) x 16 n-blocks (256 cols).
//   One-shot K=64 MFMA: A = v-tile (bf16), B rows = Wo rows (bf16) - no transpose.
//   Epilogue via per-wave LDS transpose (k_main-proven pattern).
// ---------------------------------------------------------------------------
__global__ __launch_bounds__(256, 3) void k_h(
    const float* __restrict__ x, const float* __restrict__ Wo,
    const float* __restrict__ bv, const float* __restrict__ bo,
    const float* __restrict__ Vp, u16* __restrict__ hb) {
  __shared__ __align__(16) u16 smem[64 * 72 + 256 * 72];  // lV | lW = 46080 B
  u16* lV = smem;
  u16* lW = smem + 64 * 72;
  const int tid = threadIdx.x;
  const int w = tid >> 6, l = tid & 63;
  const long m0 = (long)(blockIdx.x >> 4) * 64;
  const int c0 = (int)(blockIdx.x & 15) * 256;

  {  // phase 1: v-tile = sum_ks Vp + bv -> bf16 LDS
    int row = tid >> 2, a0 = (tid & 3) * 16;
    f32x4 s[4];
#pragma unroll
    for (int j = 0; j < 4; ++j) s[j] = *(const f32x4*)&Vp[(m0 + row) * 64 + a0 + j * 4];
#pragma unroll
    for (int ks = 1; ks < 4; ++ks)
#pragma unroll
      for (int j = 0; j < 4; ++j)
        s[j] += *(const f32x4*)&Vp[((long)ks * 8192 + m0 + row) * 64 + a0 + j * 4];
#pragma unroll
    for (int j = 0; j < 4; ++j) s[j] += *(const f32x4*)&bv[a0 + j * 4];
    u16x8 o0, o1;
#pragma unroll
    for (int e = 0; e < 4; ++e) { o0[e] = f2b(s[0][e]); o0[4 + e] = f2b(s[1][e]); }
#pragma unroll
    for (int e = 0; e < 4; ++e) { o1[e] = f2b(s[2][e]); o1[4 + e] = f2b(s[3][e]); }
    *(u16x8*)&lV[row * 72 + a0] = o0;
    *(u16x8*)&lV[row * 72 + a0 + 8] = o1;
  }
#pragma unroll
  for (int g = 0; g < 4; ++g) {  // phase 2: Wo rows c0..c0+256 -> bf16 LDS
    int row = g * 64 + (tid >> 2), cc = (tid & 3) * 16;
    cvt16(&Wo[(long)(c0 + row) * 64 + cc], &lW[row * 72 + cc], &lW[row * 72 + cc + 8]);
  }
  __syncthreads();

  // phase 3: 16x(16x16) MFMA tiles, K=64
  f32x4 acc[16];
#pragma unroll
  for (int nt = 0; nt < 16; ++nt) acc[nt] = (f32x4)(0.f);
#pragma unroll
  for (int kk = 0; kk < 2; ++kk) {
    const int ko = kk * 32 + (l >> 4) * 8;
    bf16x8 af = *(const bf16x8*)&lV[(w * 16 + (l & 15)) * 72 + ko];
#pragma unroll
    for (int nt = 0; nt < 16; ++nt) {
      bf16x8 bf = *(const bf16x8*)&lW[(nt * 16 + (l & 15)) * 72 + ko];
      acc[nt] = mfma16(af, bf, acc[nt]);
    }
  }
  __syncthreads();  // lV/lW dead; eb overlays smem

  // phase 4: h = acc + x + bo -> bf16, per-wave transpose, coalesced stores
  float* eb = ((float*)smem) + w * 1024;  // 16 rows x 64 cols fp32 per wave
#pragma unroll
  for (int g = 0; g < 4; ++g) {
#pragma unroll
    for (int q = 0; q < 4; ++q) {
      int nt = g * 4 + q;
#pragma unroll
      for (int r = 0; r < 4; ++r)
        eb[((l >> 4) * 4 + r) * 64 + q * 16 + (l & 15)] = acc[nt][r];
    }
    int rr = l >> 2, cc = (l & 3) * 16;
    long grow = m0 + w * 16 + rr;
    int gcol = c0 + g * 64 + cc;
    f32x4 h0 = *(const f32x4*)&eb[rr * 64 + cc];
    f32x4 h1 = *(const f32x4*)&eb[rr * 64 + cc + 4];
    f32x4 h2 = *(const f32x4*)&eb[rr * 64 + cc + 8];
    f32x4 h3 = *(const f32x4*)&eb[rr * 64 + cc + 12];
    h0 += *(const f32x4*)&x[grow * 4096 + gcol]     + *(const f32x4*)&bo[gcol];
    h1 += *(const f32x4*)&x[grow * 4096 + gcol + 4] + *(const f32x4*)&bo[gcol + 4];
    h2 += *(const f32x4*)&x[grow * 4096 + gcol + 8] + *(const f32x4*)&bo[gcol + 8];
    h3 += *(const f32x4*)&x[grow * 4096 + gcol + 12] + *(const f32x4*)&bo[gcol + 12];
    u16x8 o0, o1;
#pragma unroll
    for (int e = 0; e < 4; ++e) { o0[e] = f2b(h0[e]); o0[4 + e] = f2b(h1[e]); }
#pragma unroll
    for (int e = 0; e < 4; ++e) { o1[e] = f2b(h2[e]); o1[4 + e] = f2b(h3[e]); }
    *(u16x8*)&hb[grow * 4096 + gcol] = o0;
    *(u16x8*)&hb[grow * 4096 + gcol + 8] = o1;
  }
}

// ---------------------------------------------------------------------------
// k_main: out = relu(hb@Wnb^T + bn) — round-4 proven kernel, tail removed.
//   BK=64, XOR-swizzled LDS (128B rows), 64 iters, 128x128 tile, gl_lds16.
// ---------------------------------------------------------------------------
__global__ __launch_bounds__(256, 2) void k_main(
    const u16* __restrict__ X, const u16* __restrict__ Wn,
    const float* __restrict__ bn, float* __restrict__ Out) {
  __shared__ __align__(16) u16 smem[2 * 128 * 64];  // 32 KB
  u16* lA = smem;
  u16* lB = smem + 128 * 64;
  const int tid = threadIdx.x;
  const int w = tid >> 6, l = tid & 63;
  const int wRow = (w & 1) * 64, wCol = (w >> 1) * 64;
  const long mBase = (long)(blockIdx.x >> 5) * 128;
  const int nBase = (int)(blockIdx.x & 31) * 128;

  f32x4 acc[4][4];
#pragma unroll
  for (int mt = 0; mt < 4; ++mt)
#pragma unroll
    for (int nt = 0; nt < 4; ++nt) acc[mt][nt] = (f32x4)(0.f);

  const int srow = l >> 3;              // staging sub-row 0..7
  const int sp = ((l & 7) ^ srow) * 8;  // swizzled global 16B-slot (elements)

  for (int kb = 0; kb < 64; ++kb) {
    const u16* pA = X + (long)kb * 64;
    const u16* pB = Wn + (long)kb * 64;
    __syncthreads();
#pragma unroll
    for (int i = 0; i < 4; ++i) {
      int row = w * 32 + i * 8 + srow;
      gl_lds16(pA + (mBase + row) * (long)4096 + sp, lA + (w * 32 + i * 8) * 64);
      gl_lds16(pB + (long)(nBase + row) * 4096 + sp, lB + (w * 32 + i * 8) * 64);
    }
    __syncthreads();
#pragma unroll
    for (int kk = 0; kk < 2; ++kk) {
      int slot = ((kk * 4 + (l >> 4)) ^ (l & 7)) * 8;
      bf16x8 af[4], bfr[4];
#pragma unroll
      for (int mt = 0; mt < 4; ++mt)
        af[mt] = *(const bf16x8*)&lA[(wRow + mt * 16 + (l & 15)) * 64 + slot];
#pragma unroll
      for (int nt = 0; nt < 4; ++nt)
        bfr[nt] = *(const bf16x8*)&lB[(wCol + nt * 16 + (l & 15)) * 64 + slot];
#pragma unroll
      for (int mt = 0; mt < 4; ++mt)
#pragma unroll
        for (int nt = 0; nt < 4; ++nt) acc[mt][nt] = mfma16(af[mt], bfr[nt], acc[mt][nt]);
    }
  }

  // epilogue: bias + relu, fp32; per-wave LDS transpose (4 KB/wave), dwordx4 stores
  __syncthreads();
  float* eb = ((float*)smem) + w * 1024;
#pragma unroll
  for (int mt = 0; mt < 4; ++mt) {
#pragma unroll
    for (int nt = 0; nt < 4; ++nt) {
      float bt = bn[nBase + wCol + nt * 16 + (l & 15)];
#pragma unroll
      for (int r = 0; r < 4; ++r) {
        float val = acc[mt][nt][r] + bt;
        eb[((l >> 4) * 4 + r) * 64 + nt * 16 + (l & 15)] = fmaxf(val, 0.f);
      }
    }
    int rr = l >> 2, c0 = (l & 3) * 16;
    long grow = mBase + wRow + mt * 16 + rr;
    int gcol = nBase + wCol + c0;
    f32x4 o0 = *(const f32x4*)&eb[rr * 64 + c0];
    f32x4 o1 = *(const f32x4*)&eb[rr * 64 + c0 + 4];
    f32x4 o2 = *(const f32x4*)&eb[rr * 64 + c0 + 8];
    f32x4 o3 = *(const f32x4*)&eb[rr * 64 + c0 + 12];
    *(f32x4*)&Out[grow * 4096 + gcol] = o0;
    *(f32x4*)&Out[grow * 4096 + gcol + 4] = o1;
    *(f32x4*)&Out[grow * 4096 + gcol + 8] = o2;
    *(f32x4*)&Out[grow * 4096 + gcol + 12] = o3;
  }
}

// ---------------------------------------------------------------------------
extern "C" void kernel_launch(void* const* d_in, const int* in_sizes, int n_in,
                              void* d_out, int out_size, void* d_ws, size_t ws_size,
                              hipStream_t stream) {
  const float* x  = (const float*)d_in[0];
  const float* Wv = (const float*)d_in[5];
  const float* bv = (const float*)d_in[6];
  const float* Wo = (const float*)d_in[7];
  const float* bo = (const float*)d_in[8];
  const float* Wn = (const float*)d_in[9];
  const float* bn = (const float*)d_in[10];
  float* out = (float*)d_out;

  char* ws = (char*)d_ws;
  u16* hb  = (u16*)ws;                   // 8192*4096*2 = 64 MB
  u16* Wnb = (u16*)(ws + (64L << 20));   // 4096*4096*2 = 32 MB
  float* Vp = (float*)d_out;             // 4*8192*64*4 = 8 MB scratch in d_out
                                         // (k_main fully overwrites d_out afterwards)

  k_v<<<dim3(512), dim3(256), 0, stream>>>(x, Wv, Vp);
  k_cvtWn<<<dim3(8192), dim3(256), 0, stream>>>(Wn, Wnb);
  k_h<<<dim3(2048), dim3(256), 0, stream>>>(x, Wo, bv, bo, Vp, hb);
  k_main<<<dim3(2048), dim3(256), 0, stream>>>(hb, Wnb, bn, out);
}